// Round 1
// baseline (234.103 us; speedup 1.0000x reference)
//
#include <hip/hip_runtime.h>
#include <hip/hip_bf16.h>

// out = base + (base @ A2.T) @ bb.T  where A2 = M.T @ A, M = B.T @ diag(e) @ aa.T  (16x16)
// Shapes: base [N=16384 rows][D=4096], A[16][4096], E[32], B[32][16], aa[16][32], bb[4096][16]

#define D_DIM 4096
#define K_LR 16
#define R_LR 32
#define ROWS 64      // rows per block tile (lane = row)
#define DC 32        // d-chunk staged in LDS per wave
#define STRIDE 36    // DC + 4 pad: bank-conflict-free for stride-row b128 reads
#define NSPLIT 4     // d-splits across blocks
#define DWIN 1024    // per-block d window (D_DIM / NSPLIT)
#define WWIN 256     // per-wave d window (DWIN / 4 waves)

__global__ void __launch_bounds__(256) prep_kernel(const float* __restrict__ A,
                                                   const float* __restrict__ E,
                                                   const float* __restrict__ Bm,
                                                   const float* __restrict__ aa,
                                                   float* __restrict__ A2t) {
    __shared__ float Ms[K_LR][K_LR];
    const int t = threadIdx.x;
    {
        const int k = t >> 4, kp = t & 15;
        float s = 0.f;
        #pragma unroll
        for (int r = 0; r < R_LR; ++r)
            s += Bm[r * K_LR + k] * E[r] * aa[kp * R_LR + r];
        Ms[k][kp] = s;  // M[k][k'] = sum_r B[r][k] * e[r] * aa[k'][r]
    }
    __syncthreads();
    const int d = blockIdx.x * 256 + t;
    float acc[K_LR];
    #pragma unroll
    for (int kp = 0; kp < K_LR; ++kp) acc[kp] = 0.f;
    #pragma unroll
    for (int k = 0; k < K_LR; ++k) {
        const float a = A[k * D_DIM + d];
        #pragma unroll
        for (int kp = 0; kp < K_LR; ++kp) acc[kp] = fmaf(a, Ms[k][kp], acc[kp]);
    }
    #pragma unroll
    for (int kq = 0; kq < 4; ++kq) {
        float4 v = make_float4(acc[kq*4+0], acc[kq*4+1], acc[kq*4+2], acc[kq*4+3]);
        *(float4*)(A2t + (size_t)d * K_LR + kq * 4) = v;  // A2t[d][k'] d-major
    }
}

// T_partial[split][row][16] = sum over d-window of base[row][d] * A2t[d][k]
__global__ void __launch_bounds__(256) k1_kernel(const float* __restrict__ base,
                                                 const float* __restrict__ A2t,
                                                 float* __restrict__ Tp, int N) {
    __shared__ float stage[4][ROWS][STRIDE];
    __shared__ float tp[4][ROWS][K_LR];
    const int tid  = threadIdx.x;
    const int lane = tid & 63;
    const int wv   = __builtin_amdgcn_readfirstlane(tid >> 6);
    const int rowtile = blockIdx.x / NSPLIT;
    const int split   = blockIdx.x % NSPLIT;
    const int r0 = rowtile * ROWS;
    const int d0 = split * DWIN + wv * WWIN;

    float acc[K_LR];
    #pragma unroll
    for (int k = 0; k < K_LR; ++k) acc[k] = 0.f;

    for (int c = 0; c < WWIN / DC; ++c) {
        const int dc = d0 + c * DC;
        // stage 64 rows x 32 floats of base, coalesced
        #pragma unroll
        for (int i = 0; i < 8; ++i) {
            const int f = i * 64 + lane;
            const int rr = f >> 3, c4 = f & 7;
            float4 v = *(const float4*)(base + (size_t)(r0 + rr) * D_DIM + dc + c4 * 4);
            *(float4*)(&stage[wv][rr][c4 * 4]) = v;
        }
        __syncthreads();
        const float* srow = &stage[wv][lane][0];  // this lane's row
        #pragma unroll
        for (int j = 0; j < DC / 4; ++j) {
            const float4 b4 = *(const float4*)(srow + j * 4);
            const float* a2p = A2t + (size_t)(dc + j * 4) * K_LR;  // wave-uniform -> s_load
            #pragma unroll
            for (int jj = 0; jj < 4; ++jj) {
                const float bv = (&b4.x)[jj];
                #pragma unroll
                for (int k = 0; k < K_LR; ++k)
                    acc[k] = fmaf(bv, a2p[jj * K_LR + k], acc[k]);
            }
        }
        __syncthreads();
    }
    #pragma unroll
    for (int kq = 0; kq < 4; ++kq)
        *(float4*)(&tp[wv][lane][kq * 4]) =
            make_float4(acc[kq*4+0], acc[kq*4+1], acc[kq*4+2], acc[kq*4+3]);
    __syncthreads();
    {   // block-reduce the 4 wave partials; 256 threads x one float4 each
        const int row = tid >> 2, kq = tid & 3;
        float4 s = make_float4(0.f, 0.f, 0.f, 0.f);
        #pragma unroll
        for (int w = 0; w < 4; ++w) {
            float4 v = *(const float4*)(&tp[w][row][kq * 4]);
            s.x += v.x; s.y += v.y; s.z += v.z; s.w += v.w;
        }
        *(float4*)(Tp + ((size_t)split * N + r0 + row) * K_LR + kq * 4) = s;
    }
}

// out[row][d] = base[row][d] + sum_k t4[row][k] * bb[d][k],  t4 = sum of 4 partials
__global__ void __launch_bounds__(256) k2_kernel(const float* __restrict__ base,
                                                 const float* __restrict__ bb,
                                                 const float* __restrict__ Tp,
                                                 float* __restrict__ out, int N) {
    __shared__ float stage[4][ROWS][STRIDE];
    const int tid  = threadIdx.x;
    const int lane = tid & 63;
    const int wv   = __builtin_amdgcn_readfirstlane(tid >> 6);
    const int rowtile = blockIdx.x / NSPLIT;
    const int split   = blockIdx.x % NSPLIT;
    const int r0 = rowtile * ROWS;
    const int d0 = split * DWIN + wv * WWIN;

    float t4[K_LR];
    #pragma unroll
    for (int kq = 0; kq < 4; ++kq) {
        float4 s = make_float4(0.f, 0.f, 0.f, 0.f);
        #pragma unroll
        for (int sp = 0; sp < NSPLIT; ++sp) {
            float4 v = *(const float4*)(Tp + ((size_t)sp * N + r0 + lane) * K_LR + kq * 4);
            s.x += v.x; s.y += v.y; s.z += v.z; s.w += v.w;
        }
        t4[kq*4+0] = s.x; t4[kq*4+1] = s.y; t4[kq*4+2] = s.z; t4[kq*4+3] = s.w;
    }

    for (int c = 0; c < WWIN / DC; ++c) {
        const int dc = d0 + c * DC;
        #pragma unroll
        for (int i = 0; i < 8; ++i) {
            const int f = i * 64 + lane;
            const int rr = f >> 3, c4 = f & 7;
            float4 v = *(const float4*)(base + (size_t)(r0 + rr) * D_DIM + dc + c4 * 4);
            *(float4*)(&stage[wv][rr][c4 * 4]) = v;
        }
        __syncthreads();
        float* srow = &stage[wv][lane][0];
        #pragma unroll
        for (int j = 0; j < DC / 4; ++j) {
            const float4 b4 = *(const float4*)(srow + j * 4);
            float4 r4;
            #pragma unroll
            for (int jj = 0; jj < 4; ++jj) {
                const float* bp = bb + (size_t)(dc + j * 4 + jj) * K_LR;  // uniform -> s_load
                float o = (&b4.x)[jj];
                #pragma unroll
                for (int k = 0; k < K_LR; ++k)
                    o = fmaf(t4[k], bp[k], o);
                (&r4.x)[jj] = o;
            }
            *(float4*)(srow + j * 4) = r4;  // in-place: base tile -> out tile
        }
        __syncthreads();
        #pragma unroll
        for (int i = 0; i < 8; ++i) {
            const int f = i * 64 + lane;
            const int rr = f >> 3, c4 = f & 7;
            float4 v = *(const float4*)(&stage[wv][rr][c4 * 4]);
            *(float4*)(out + (size_t)(r0 + rr) * D_DIM + dc + c4 * 4) = v;
        }
        __syncthreads();
    }
}

extern "C" void kernel_launch(void* const* d_in, const int* in_sizes, int n_in,
                              void* d_out, int out_size, void* d_ws, size_t ws_size,
                              hipStream_t stream) {
    const float* base = (const float*)d_in[0];
    const float* A    = (const float*)d_in[1];
    const float* E    = (const float*)d_in[2];
    const float* Bm   = (const float*)d_in[3];
    const float* aa   = (const float*)d_in[4];
    const float* bb   = (const float*)d_in[5];
    float* out = (float*)d_out;
    const int N = in_sizes[0] / D_DIM;  // 16384 rows

    float* A2t = (float*)d_ws;                                       // 256 KiB
    float* Tp  = (float*)((char*)d_ws + (size_t)D_DIM * K_LR * 4);   // 4 MiB

    prep_kernel<<<D_DIM / 256, 256, 0, stream>>>(A, E, Bm, aa, A2t);
    k1_kernel<<<(N / ROWS) * NSPLIT, 256, 0, stream>>>(base, A2t, Tp, N);
    k2_kernel<<<(N / ROWS) * NSPLIT, 256, 0, stream>>>(base, bb, Tp, out, N);
}

// Round 3
// 164.560 us; speedup vs baseline: 1.4226x; 1.4226x over previous
//
#include <hip/hip_runtime.h>
#include <hip/hip_bf16.h>

// out = base + (base @ A2.T) @ bb.T  where A2 = M.T @ A, M = B.T @ diag(e) @ aa.T  (16x16)
// base [N=16384 rows][D=4096], A[16][4096], E[32], B[32][16], aa[16][32], bb[4096][16]

#define D_DIM 4096
#define K_LR 16
#define R_LR 32
#define ROWS 64       // rows per block tile
#define DC 32         // d-chunk staged in LDS per wave (128 B per row)
#define NSPLIT 4      // d-splits across blocks (k1)
#define DWIN 1024     // per-block d window
#define WWIN 256      // per-wave d window
#define NCH (WWIN / DC)   // 8 chunks
#define NPART 16      // NSPLIT * 4 waves partials

typedef float f32x4 __attribute__((ext_vector_type(4)));

__global__ void __launch_bounds__(256) prep_kernel(const float* __restrict__ A,
                                                   const float* __restrict__ E,
                                                   const float* __restrict__ Bm,
                                                   const float* __restrict__ aa,
                                                   float* __restrict__ A2t) {
    __shared__ float Ms[K_LR][K_LR];
    const int t = threadIdx.x;
    {
        const int k = t >> 4, kp = t & 15;
        float s = 0.f;
        #pragma unroll
        for (int r = 0; r < R_LR; ++r)
            s += Bm[r * K_LR + k] * E[r] * aa[kp * R_LR + r];
        Ms[k][kp] = s;  // M[k][k'] = sum_r B[r][k] * e[r] * aa[k'][r]
    }
    __syncthreads();
    const int d = blockIdx.x * 256 + t;
    float acc[K_LR];
    #pragma unroll
    for (int kp = 0; kp < K_LR; ++kp) acc[kp] = 0.f;
    #pragma unroll
    for (int k = 0; k < K_LR; ++k) {
        const float a = A[k * D_DIM + d];
        #pragma unroll
        for (int kp = 0; kp < K_LR; ++kp) acc[kp] = fmaf(a, Ms[k][kp], acc[kp]);
    }
    #pragma unroll
    for (int kq = 0; kq < 4; ++kq) {
        f32x4 v = { acc[kq*4+0], acc[kq*4+1], acc[kq*4+2], acc[kq*4+3] };
        *(f32x4*)(A2t + (size_t)d * K_LR + kq * 4) = v;  // A2t[d][k'] d-major
    }
}

// k1: Tp[wave_split][row][16] = sum over wave's 256-col window of base[row][d]*A2t[d][k]
// Barrier-free: stage[] is wave-private; XOR-swizzled LDS, reg-staged prefetch.
__global__ void __launch_bounds__(256) k1_kernel(const float* __restrict__ base,
                                                 const float* __restrict__ A2t,
                                                 float* __restrict__ Tp, int N) {
    __shared__ float stage[4][ROWS][DC];  // 32 KiB, per-wave 8 KiB quadrants
    const int tid  = threadIdx.x;
    const int lane = tid & 63;
    const int wv   = __builtin_amdgcn_readfirstlane(tid >> 6);
    const int a    = lane >> 3;          // row-within-8-group for staging
    const int b    = lane & 7;           // col4-group for staging
    const int rowtile = blockIdx.x / NSPLIT;
    const int split   = blockIdx.x % NSPLIT;
    const int r0 = rowtile * ROWS;
    const int d0 = split * DWIN + wv * WWIN;

    char* wbase = (char*)&stage[wv][0][0];
    const int swz_w = 16 * (b ^ a);      // swizzled 16B slot for staging write
    const int swz_r = (lane & 7) << 4;   // read-side XOR (row = lane)

    float acc[K_LR];
    #pragma unroll
    for (int k = 0; k < K_LR; ++k) acc[k] = 0.f;

    f32x4 st[8];
    // prologue: load chunk 0 into regs
    #pragma unroll
    for (int i = 0; i < 8; ++i)
        st[i] = *(const f32x4*)(base + (size_t)(r0 + i*8 + a) * D_DIM + d0 + 4*b);

    for (int c = 0; c < NCH; ++c) {
        // stage chunk c: regs -> LDS (swizzled, conflict-free permutation)
        #pragma unroll
        for (int i = 0; i < 8; ++i)
            *(f32x4*)(wbase + (i*8 + a) * 128 + swz_w) = st[i];
        // prefetch chunk c+1 into regs (overlaps with compute below)
        if (c + 1 < NCH) {
            const int dcn = d0 + (c + 1) * DC;
            #pragma unroll
            for (int i = 0; i < 8; ++i)
                st[i] = *(const f32x4*)(base + (size_t)(r0 + i*8 + a) * D_DIM + dcn + 4*b);
        }
        // compute chunk c: lane = row; A2t via wave-uniform scalar loads
        const int dc = d0 + c * DC;
        #pragma unroll
        for (int j = 0; j < DC/4; ++j) {
            const f32x4 b4 = *(const f32x4*)(wbase + lane * 128 + ((16*j) ^ swz_r));
            const float* a2p = A2t + (size_t)(dc + 4*j) * K_LR;
            #pragma unroll
            for (int jj = 0; jj < 4; ++jj) {
                const float bv = b4[jj];
                #pragma unroll
                for (int k = 0; k < K_LR; ++k)
                    acc[k] = fmaf(bv, a2p[jj * K_LR + k], acc[k]);
            }
        }
    }
    // each wave writes its own partial; no cross-wave reduce, no barrier
    const int ws = split * 4 + wv;
    float* tp = Tp + ((size_t)ws * N + r0 + lane) * K_LR;
    #pragma unroll
    for (int kq = 0; kq < 4; ++kq) {
        f32x4 v = { acc[kq*4+0], acc[kq*4+1], acc[kq*4+2], acc[kq*4+3] };
        *(f32x4*)(tp + kq * 4) = v;
    }
}

// k1b: T[i] = sum of 16 partials
__global__ void __launch_bounds__(256) k1b_kernel(const float* __restrict__ Tp,
                                                  float* __restrict__ T, int N) {
    const int g = blockIdx.x * 256 + threadIdx.x;      // float4 index, < N*16/4
    const size_t stride = (size_t)N * K_LR / 4;
    const f32x4* tp4 = (const f32x4*)Tp;
    f32x4 s = tp4[g];
    #pragma unroll
    for (int ws = 1; ws < NPART; ++ws)
        s += tp4[ws * stride + g];
    ((f32x4*)T)[g] = s;
}

// k2: out[row][d] = base[row][d] + sum_k T[row][k]*bb[d][k]
// No LDS: lane=4 cols, bb window register-resident, T via wave-uniform s_loads.
__global__ void __launch_bounds__(256) k2_kernel(const float* __restrict__ base,
                                                 const float* __restrict__ bb,
                                                 const float* __restrict__ T,
                                                 float* __restrict__ out, int N) {
    const int tid  = threadIdx.x;
    const int lane = tid & 63;
    const int wv   = __builtin_amdgcn_readfirstlane(tid >> 6);
    const int rowtile = blockIdx.x >> 2;          // N/64 rowtiles
    const int dwin    = blockIdx.x & 3;           // 4 d-windows of 1024
    const int r0 = rowtile * ROWS;
    const int cbase = dwin * 1024 + wv * 256 + lane * 4;  // this lane's 4 cols

    // bb[cbase..cbase+3][0..15] -> 64 VGPRs, read once per block
    f32x4 bbr[4][4];
    #pragma unroll
    for (int q = 0; q < 4; ++q)
        #pragma unroll
        for (int kq = 0; kq < 4; ++kq)
            bbr[q][kq] = *(const f32x4*)(bb + (size_t)(cbase + q) * K_LR + kq * 4);

    #pragma unroll 2
    for (int r = 0; r < ROWS; ++r) {
        const size_t row = (size_t)(r0 + r);
        const float* tp = T + row * K_LR;          // wave-uniform -> s_load
        float t16[K_LR];
        #pragma unroll
        for (int k = 0; k < K_LR; ++k) t16[k] = tp[k];

        const f32x4 bv = *(const f32x4*)(base + row * D_DIM + cbase);
        f32x4 ov;
        #pragma unroll
        for (int q = 0; q < 4; ++q) {
            float o = bv[q];
            #pragma unroll
            for (int k = 0; k < K_LR; ++k)
                o = fmaf(t16[k], bbr[q][k >> 2][k & 3], o);
            ov[q] = o;
        }
        __builtin_nontemporal_store(ov, (f32x4*)(out + row * D_DIM + cbase));
    }
}

extern "C" void kernel_launch(void* const* d_in, const int* in_sizes, int n_in,
                              void* d_out, int out_size, void* d_ws, size_t ws_size,
                              hipStream_t stream) {
    const float* base = (const float*)d_in[0];
    const float* A    = (const float*)d_in[1];
    const float* E    = (const float*)d_in[2];
    const float* Bm   = (const float*)d_in[3];
    const float* aa   = (const float*)d_in[4];
    const float* bb   = (const float*)d_in[5];
    float* out = (float*)d_out;
    const int N = in_sizes[0] / D_DIM;  // 16384 rows

    float* A2t = (float*)d_ws;                                   // 256 KiB @ 0
    float* Tp  = (float*)((char*)d_ws + (1u << 20));             // 16 MiB @ 1 MiB
    float* T   = (float*)((char*)d_ws + (32u << 20));            // 1 MiB  @ 32 MiB

    prep_kernel<<<D_DIM / 256, 256, 0, stream>>>(A, E, Bm, aa, A2t);
    k1_kernel<<<(N / ROWS) * NSPLIT, 256, 0, stream>>>(base, A2t, Tp, N);
    k1b_kernel<<<(N * K_LR / 4) / 256, 256, 0, stream>>>(Tp, T, N);
    k2_kernel<<<(N / ROWS) * 4, 256, 0, stream>>>(base, bb, T, out, N);
}